// Round 10
// baseline (275.400 us; speedup 1.0000x reference)
//
#include <hip/hip_runtime.h>

// Problem: B=2048, D=2048, N=64 transforms, R=32.
//  out0 (2048x2048 f32) = sum_n gate[b,n] * (x V_n^T U_n^T)
//  out1 (2048x64  f32) = jumprelu(x enc^T - bias)
//  out2 (64 f32)       = ||U_n||_F ||V_n||_F / 256
// Flatten (n,r)->c=2048: two 2048^3 bf16 MFMA GEMMs (R7 champion config:
// 128x64 tiles, TEAMS=2 wave-split-K, SWZ grid 512, 2 blocks/CU).
// R9->R10: revert R9's tail-ridden merged GEMM1 (grid 528 => 16-block
// serial tail, +15us). Harvest overhead instead: gate computed as f32
// VALU dot inside k_prep (overlaps memory-bound convert blocks; kills
// gate-GEMM + gate_reduce + encb), frob folded into GEMM1 block 0.
// Launches 6 -> 3.

#define D_MODEL 2048
#define BATCH   2048
#define NT      64
#define RANK    32

typedef __attribute__((ext_vector_type(8))) __bf16 bf16x8;
typedef __attribute__((ext_vector_type(4))) float  f32x4;

__device__ __forceinline__ unsigned short f2bf(float f) {
  unsigned int u = __builtin_bit_cast(unsigned int, f);
  u += 0x7FFFu + ((u >> 16) & 1u);          // RNE
  return (unsigned short)(u >> 16);
}

// async global->LDS, 16B per lane. LDS dest is wave-uniform base + lane*16.
__device__ __forceinline__ void gload_lds16(const void* g, void* l) {
  __builtin_amdgcn_global_load_lds(
      (const __attribute__((address_space(1))) unsigned int*)g,
      (__attribute__((address_space(3))) unsigned int*)l,
      16, 0, 0);
}

// ---------------- merged prep ----------------
// blocks [0,1024): x->bf16          [1024,1280): V->bf16 (+sumsq)
// blocks [1280,1536): U->Ut (+sumsq) [1536,1664): gate via f32 VALU dot

__device__ __forceinline__ void block_reduce_store(float ss, float* dst, int slot) {
  __shared__ float red[256];
  int t = threadIdx.x;
  red[t] = ss;
  __syncthreads();
  for (int s = 128; s > 0; s >>= 1) {
    if (t < s) red[t] += red[t + s];
    __syncthreads();
  }
  if (t == 0) dst[slot] = red[0];
}

__global__ void k_prep(const float4* __restrict__ x, const float4* __restrict__ enc,
                       const float4* __restrict__ V, const float4* __restrict__ U,
                       const float* __restrict__ bias,
                       ushort4* __restrict__ xb, ushort4* __restrict__ Vb,
                       unsigned short* __restrict__ Ut,
                       float* __restrict__ partV, float* __restrict__ partU,
                       float* __restrict__ gate) {
  int bid = blockIdx.x, t = threadIdx.x;
  if (bid < 1024) {                      // x: 1048576 float4, 1024 per block
#pragma unroll
    for (int it = 0; it < 4; ++it) {
      int i = bid * 1024 + it * 256 + t;
      float4 v = x[i];
      ushort4 o;
      o.x = f2bf(v.x); o.y = f2bf(v.y); o.z = f2bf(v.z); o.w = f2bf(v.w);
      xb[i] = o;
    }
  } else if (bid < 1280) {               // V: contiguous convert + sumsq
    int b = bid - 1024;                  // 256 blocks
    size_t base4 = (size_t)b * 4096;
    float ss = 0.f;
    for (int it = 0; it < 16; ++it) {
      size_t idx = base4 + t + it * 256;
      float4 v = V[idx];
      ss += v.x * v.x + v.y * v.y + v.z * v.z + v.w * v.w;
      ushort4 o;
      o.x = f2bf(v.x); o.y = f2bf(v.y); o.z = f2bf(v.z); o.w = f2bf(v.w);
      Vb[idx] = o;
    }
    block_reduce_store(ss, partV, b);
  } else if (bid < 1536) {               // U: transpose-convert + sumsq
    int b = bid - 1280;
    int n = b >> 2;
    size_t base4 = (size_t)b * 4096;
    float ss = 0.f;
    for (int it = 0; it < 16; ++it) {
      size_t idx4 = base4 + t + it * 256;
      float4 v = U[idx4];
      ss += v.x * v.x + v.y * v.y + v.z * v.z + v.w * v.w;
      size_t e = idx4 * 4 - (size_t)n * (D_MODEL * RANK);
      int dcol = (int)(e >> 5);
      int r = (int)(e & 31);
      ushort4 o;
      o.x = f2bf(v.x); o.y = f2bf(v.y); o.z = f2bf(v.z); o.w = f2bf(v.w);
      *(ushort4*)(Ut + (size_t)dcol * 2048 + n * 32 + r) = o;
    }
    block_reduce_store(ss, partU, b);
  } else {                               // gate: f32 dot, 16 rows x 64 n / block
    int b = bid - 1536;                  // 128 blocks
    int wv = t >> 6;                     // wave id 0..3 -> row group
    int n = t & 63;
    int r0 = b * 16 + wv * 4;
    const float4* xr = x + (size_t)r0 * 512;       // 4 rows, wave-uniform
    const float4* er = enc + (size_t)n * 512;      // per-lane enc row
    float a0 = 0.f, a1 = 0.f, a2 = 0.f, a3 = 0.f;
    for (int k = 0; k < 512; ++k) {
      float4 e = er[k];
      float4 p0 = xr[k];
      float4 p1 = xr[512 + k];
      float4 p2 = xr[1024 + k];
      float4 p3 = xr[1536 + k];
      a0 += p0.x * e.x + p0.y * e.y + p0.z * e.z + p0.w * e.w;
      a1 += p1.x * e.x + p1.y * e.y + p1.z * e.z + p1.w * e.w;
      a2 += p2.x * e.x + p2.y * e.y + p2.z * e.z + p2.w * e.w;
      a3 += p3.x * e.x + p3.y * e.y + p3.z * e.z + p3.w * e.w;
    }
    float bi = bias[n];
    a0 -= bi; a1 -= bi; a2 -= bi; a3 -= bi;
    gate[(size_t)(r0 + 0) * NT + n] = a0 > 0.f ? a0 : 0.f;
    gate[(size_t)(r0 + 1) * NT + n] = a1 > 0.f ? a1 : 0.f;
    gate[(size_t)(r0 + 2) * NT + n] = a2 > 0.f ? a2 : 0.f;
    gate[(size_t)(r0 + 3) * NT + n] = a3 > 0.f ? a3 : 0.f;
  }
}

// ---------------- GEMM (BK=64, XOR-swizzled LDS, wave-split-K TEAMS=2) ----
// A: M x K row-major bf16. Bt: N x K row-major bf16. 512 threads, two
// 4-wave teams; team t covers K-half [t*K/2, +K/2) in its own LDS buffer;
// team1 accumulators LDS-reduced into team0. SWZ grid 512: lin%8 = XCD
// owns an 8x8 tile region (16 (M/128) x 32 (N/64) tiles; ~6 MB/XCD).
// EPI 0: outB[row*2048+col] = bf16(acc * gate[row*64 + col>>5]); block 0
//        also writes frob (Frobenius norms) from prep partials.
// EPI 1: outF[row*2048+col] = acc
template <int WGM, int WGN, int MI, int NJ, int EPI>
__global__ __launch_bounds__(512, 4)
void gemm_bt(const unsigned short* __restrict__ A,
             const unsigned short* __restrict__ Bt,
             const float* __restrict__ aux,
             unsigned short* __restrict__ outB,
             float* __restrict__ outF,
             const float* __restrict__ pU, const float* __restrict__ pV,
             float* __restrict__ frob, int K) {
  constexpr int BM = WGM * MI * 16;
  constexpr int BN = WGN * NJ * 16;
  constexpr int RA = BM / 32;
  constexpr int RB = BN / 32;
  __shared__ __align__(16) unsigned short smem[2 * (BM + BN) * 64];

  const int tid = threadIdx.x;
  const int w = tid >> 6;
  const int lane = tid & 63;
  const int quad = lane >> 4;
  const int l15 = lane & 15;
  const int team = w >> 2;               // 4 waves per team
  const int wl = w & 3;
  const int wm = wl % WGM;
  const int wn = wl / WGM;

  if constexpr (EPI == 0) {              // frob epilogue folded here
    if (blockIdx.x == 0 && tid < NT) {
      float su = pU[4 * tid] + pU[4 * tid + 1] + pU[4 * tid + 2] + pU[4 * tid + 3];
      float sv = pV[4 * tid] + pV[4 * tid + 1] + pV[4 * tid + 2] + pV[4 * tid + 3];
      frob[tid] = sqrtf(su) * sqrtf(sv) * (1.0f / 256.0f);
    }
  }

  unsigned short* As = smem + team * (BM + BN) * 64;
  unsigned short* Bs = As + BM * 64;

  // grid 512 = 16 (M/128) x 32 (N/64) tiles; lin%8 -> XCD, 8x8 region
  const int lin = blockIdx.x;
  const int xcd = lin & 7;
  const int i0 = lin >> 3;               // 0..63 within XCD
  const int blockM = (xcd & 1) * 8 + (i0 & 7);    // [0,16)
  const int blockN = (xcd >> 1) * 8 + (i0 >> 3);  // [0,32)
  const int kspan = K / 2;
  const int kbeg = team * kspan;

  // staging: linear LDS slot (row=l>>3, pchunk=l&7) holds logical chunk
  // q = pchunk ^ (row&7)  (XOR swizzle, involutive)
  const int lrow = lane >> 3;
  const int lq = (lane & 7) ^ lrow;
  const unsigned short* Ag = A + (size_t)(blockM * BM + lrow) * K + kbeg + lq * 8;
  const unsigned short* Bg = Bt + (size_t)(blockN * BN + lrow) * K + kbeg + lq * 8;

  // fragment: A[m=l15][k=quad*8+j]; physical chunk = (s*4+quad)^(row&7)
  const int pcs = (quad ^ (lane & 7)) * 16;
  const int rfA = wm * MI * 16 + l15;
  const int rfB = wn * NJ * 16 + l15;

  f32x4 acc[MI][NJ];
  const f32x4 z = {0.f, 0.f, 0.f, 0.f};
#pragma unroll
  for (int i = 0; i < MI; ++i)
#pragma unroll
    for (int j = 0; j < NJ; ++j) acc[i][j] = z;

  for (int k0 = 0; k0 < kspan; k0 += 64) {
#pragma unroll
    for (int j = 0; j < RA; ++j)
      gload_lds16(Ag + (size_t)((j * 4 + wl) * 8) * K + k0,
                  (char*)As + (j * 4 + wl) * 1024);
#pragma unroll
    for (int j = 0; j < RB; ++j)
      gload_lds16(Bg + (size_t)((j * 4 + wl) * 8) * K + k0,
                  (char*)Bs + (j * 4 + wl) * 1024);
    __syncthreads();
#pragma unroll
    for (int s = 0; s < 2; ++s) {
      bf16x8 af[MI], bfr[NJ];
#pragma unroll
      for (int i = 0; i < MI; ++i)
        af[i] = *(const bf16x8*)((const char*)As + (rfA + i * 16) * 128 + (pcs ^ (s << 6)));
#pragma unroll
      for (int j = 0; j < NJ; ++j)
        bfr[j] = *(const bf16x8*)((const char*)Bs + (rfB + j * 16) * 128 + (pcs ^ (s << 6)));
#pragma unroll
      for (int i = 0; i < MI; ++i)
#pragma unroll
        for (int j = 0; j < NJ; ++j)
          acc[i][j] = __builtin_amdgcn_mfma_f32_16x16x32_bf16(af[i], bfr[j], acc[i][j], 0, 0, 0);
    }
    __syncthreads();
  }

  // team reduction through LDS (staging space dead after last barrier)
  float4* red = (float4*)smem;
  const int rslot = ((wl * MI) * NJ) * 64 + lane;
  if (team == 1) {
#pragma unroll
    for (int i = 0; i < MI; ++i)
#pragma unroll
      for (int j = 0; j < NJ; ++j)
        red[rslot + (i * NJ + j) * 64] =
            (float4){acc[i][j][0], acc[i][j][1], acc[i][j][2], acc[i][j][3]};
  }
  __syncthreads();
  if (team == 1) return;
#pragma unroll
  for (int i = 0; i < MI; ++i)
#pragma unroll
    for (int j = 0; j < NJ; ++j) {
      float4 r = red[rslot + (i * NJ + j) * 64];
      acc[i][j][0] += r.x; acc[i][j][1] += r.y;
      acc[i][j][2] += r.z; acc[i][j][3] += r.w;
    }

  // epilogue (team0): C/D layout col=lane&15, row=quad*4+reg
  const int row0 = blockM * BM + wm * MI * 16 + quad * 4;
  const int col0 = blockN * BN + wn * NJ * 16 + l15;
#pragma unroll
  for (int i = 0; i < MI; ++i) {
#pragma unroll
    for (int j = 0; j < NJ; ++j) {
      const int col = col0 + j * 16;
#pragma unroll
      for (int t = 0; t < 4; ++t) {
        const int row = row0 + i * 16 + t;
        float v = acc[i][j][t];
        if constexpr (EPI == 0) {
          float g = aux[(size_t)row * NT + (col >> 5)];
          outB[(size_t)row * 2048 + col] = f2bf(v * g);
        } else {
          outF[(size_t)row * 2048 + col] = v;
        }
      }
    }
  }
}

// ---------------- launch ----------------

extern "C" void kernel_launch(void* const* d_in, const int* in_sizes, int n_in,
                              void* d_out, int out_size, void* d_ws, size_t ws_size,
                              hipStream_t stream) {
  const float* x    = (const float*)d_in[0];
  const float* V    = (const float*)d_in[1];
  const float* U    = (const float*)d_in[2];
  const float* enc  = (const float*)d_in[3];
  const float* bias = (const float*)d_in[4];

  float* out  = (float*)d_out;                        // 2048*2048
  float* gate = out + (size_t)BATCH * D_MODEL;        // 2048*64
  float* frob = gate + (size_t)BATCH * NT;            // 64

  char* ws = (char*)d_ws;                             // ~32 MB used
  unsigned short* xb = (unsigned short*)(ws);                       // 8 MB
  unsigned short* Vb = (unsigned short*)(ws + (8u << 20));          // 8 MB
  unsigned short* Ut = (unsigned short*)(ws + (16u << 20));         // 8 MB
  unsigned short* Yg = (unsigned short*)(ws + (24u << 20));         // 8 MB
  float* partU = (float*)(ws + (32u << 20));
  float* partV = partU + 256;

  // prep: conversions + U transpose + Frobenius partials + f32 VALU gate
  k_prep<<<1664, 256, 0, stream>>>((const float4*)x, (const float4*)enc,
                                   (const float4*)V, (const float4*)U, bias,
                                   (ushort4*)xb, (ushort4*)Vb, Ut,
                                   partV, partU, gate);

  // Yg = bf16(gate .* (x @ Vflat^T)): 2048^3, 128x64, TEAMS=2, 2 blk/CU
  // (+ frob in block 0)
  gemm_bt<2, 2, 4, 2, 0><<<dim3(512), 512, 0, stream>>>(
      xb, Vb, gate, Yg, nullptr, partU, partV, frob, D_MODEL);

  // out = Yg @ Ut^T: 2048^3, fp32 store
  gemm_bt<2, 2, 4, 2, 1><<<dim3(512), 512, 0, stream>>>(
      Yg, Ut, nullptr, nullptr, out, nullptr, nullptr, nullptr, D_MODEL);
}